// Round 5
// baseline (195.533 us; speedup 1.0000x reference)
//
#include <hip/hip_runtime.h>

// B=2, N=8192, K=10, I=3, LEN_IN=66. All buffers f32.
// LOCKED correctness recipe (R8-R12, passed, absmax 0.0625):
//   sq  = fmaf(z,z, fmaf(y,y, rn(x*x)))          (asc FMA)
//   dot = fmaf(z,z', fmaf(y,y', rn(x*x')))       (asc FMA)
//   d2  = fmaf(-2,dot, rn(sq_q + sq_c))          (== single-rounded sub form)
//   selection: strict <, stable lowest-index-first (lexicographic (d2,idx))
// R16: cross-wave shared threshold round.
//   Budget from R13-R15 (all scheduling tweaks neutral, 117-121us): insert
//   chain ~74K cyc/SIMD vs scan ~29K. Cause: each wave prunes only vs its
//   slice-local 11th (53+ pushes/lane); the GLOBAL 11th is ~5x tighter.
//   Fix: per-query shared bound thrG[64] in LDS. At every flush a wave
//   publishes enc(d10) via ds_min_rtn_u32 and sets
//     thr = min(d10, nextafter_up(dec(thrG)))
//   Safety: any wave's local 11th >= global 11th at all times; the bound is
//   applied NON-strict (via enc+1) so no true top-11 member is pruned; the
//   merge then recovers the exact global top-11 from the union. Hot path
//   unchanged (same `dd < thr`). Forced flush every 64 candidates keeps the
//   bound tightening once TRIG stops firing.
// R17/R18: identical resubmissions — both prior benches died at container
//   acquire (infra-level error string; kernel never executed). Three audits
//   found no kernel-side kill path: flush loop bounded + wave-uniform exit;
//   cnt<=14=DEPTH with padded prefetch row; LDS 157.5KB<160KB (same block
//   size as R14/R15); LDS atomicMin advisory (no cross-wave wait); barriers
//   in uniform control flow; enc+1 cannot overflow (bound published first).
#define NPTS   8192
#define KNN    11
#define QPB    64          // queries per block (one per lane)
#define NTHR   1024
#define NSLICE 16          // candidate slices (one per wave)
#define SLEN   (NPTS / NSLICE)   // 512
#define DEPTH  14          // per-lane push-buffer entries
#define TRIG   11          // flush when any lane cnt >= TRIG (+4 headroom -> 14 hit at check)

__global__ __launch_bounds__(NTHR, 4) void knn_mlp(
    const float* __restrict__ pos,
    const float* __restrict__ vel,
    const float* __restrict__ initc,
    const float* __restrict__ W1,
    const float* __restrict__ b1,
    const float* __restrict__ W2,
    const float* __restrict__ b2,
    const float* __restrict__ W3,
    const float* __restrict__ b3,
    float* __restrict__ out) {

    // Phased LDS (~154KB):
    //   phase-scan : [0,32K) ssq | [32K, 32K+15*8K) push region [k][tid] u64
    //                (row DEPTH is prefetch padding, never inserted)
    //   phase-fold : [32K, ...) fold scratch (4.3KB)
    //   phase-merge: [0,45K) pd f32 | [45K,90K) pi i32   (ssq/region dead)
    __shared__ __align__(16) char smem[32 * 1024 + NTHR * (DEPTH + 1) * 8];
    __shared__ float sW[405];           // Weff[396] + bias[6] + init[3]
    __shared__ unsigned thrG[QPB];      // per-query shared bound, enc-domain

    float* ssq = (float*)smem;
    unsigned long long* region = (unsigned long long*)(smem + 32 * 1024);

    const int tid  = threadIdx.x;
    const int lane = tid & 63;
    const int wave = __builtin_amdgcn_readfirstlane(tid >> 6);  // provably uniform
    const int b    = blockIdx.x >> 7;           // 128 blocks per batch
    const int n0   = (blockIdx.x & 127) * QPB;
    const int q    = n0 + lane;

    const float* posb = pos + b * NPTS * 3;
    const float* velb = vel + b * NPTS * 3;

    // ---- phase 1a: per-point sq into LDS (LOCKED recipe)
    for (int a = tid; a < NPTS; a += NTHR) {
        float x = posb[a * 3 + 0];
        float y = posb[a * 3 + 1];
        float z = posb[a * 3 + 2];
        ssq[a] = __fmaf_rn(z, z, __fmaf_rn(y, y, __fmul_rn(x, x)));
    }
    // ---- phase 1b: fold stage 1 (scratch in region): W12 = W1@W2, b12 = b1@W2+b2
    float* sW12 = (float*)region;
    for (int e = tid; e < 66 * 16; e += NTHR) {
        int r = e >> 4, c = e & 15;
        float s = 0.f;
        for (int j = 0; j < 32; ++j) s += W1[r * 32 + j] * W2[j * 16 + c];
        sW12[e] = s;
    }
    if (tid < 16) {
        float s = b2[tid];
        for (int j = 0; j < 32; ++j) s += b1[j] * W2[j * 16 + tid];
        sW12[66 * 16 + tid] = s;
    }
    if (tid < 3) sW[402 + tid] = initc[b * 3 + tid];
    if (tid < QPB) thrG[tid] = 0xFF800000u;     // enc(+inf): no bound yet
    __syncthreads();
    // ---- fold stage 2: Weff = W12@W3, bias = b12@W3 + b3
    for (int e = tid; e < 66 * 6; e += NTHR) {
        int r = e / 6, c = e - r * 6;
        float s = 0.f;
        for (int j = 0; j < 16; ++j) s += sW12[r * 16 + j] * W3[j * 6 + c];
        sW[e] = s;
    }
    if (tid < 6) {
        float s = b3[tid];
        for (int j = 0; j < 16; ++j) s += sW12[66 * 16 + j] * W3[j * 6 + tid];
        sW[396 + tid] = s;
    }
    __syncthreads();   // fold scratch done -> region becomes push buffers

    const float qx = posb[q * 3 + 0];
    const float qy = posb[q * 3 + 1];
    const float qz = posb[q * 3 + 2];
    const float sqq = ssq[q];           // identical bits to locked recipe

    // Top-11 in NAMED SCALARS (forced register residency; R12 demoted arrays).
    float d0 = 3.0e38f, d1 = 3.0e38f, d2v = 3.0e38f, d3 = 3.0e38f, d4 = 3.0e38f,
          d5 = 3.0e38f, d6 = 3.0e38f, d7 = 3.0e38f, d8 = 3.0e38f, d9 = 3.0e38f,
          d10 = 3.0e38f;
    int   i0 = 0x7FFFFFFF, i1 = 0x7FFFFFFF, i2v = 0x7FFFFFFF, i3 = 0x7FFFFFFF,
          i4 = 0x7FFFFFFF, i5 = 0x7FFFFFFF, i6 = 0x7FFFFFFF, i7 = 0x7FFFFFFF,
          i8 = 0x7FFFFFFF, i9 = 0x7FFFFFFF, i10 = 0x7FFFFFFF;

    float thr = 3.0e38f;       // combined bound; only over-buffers, never drops
    int cnt = 0;

    // Hand-unrolled stable insert (identical semantics to the array loop).
    auto insert = [&](float nd, int nj) {
        if (nd < d10) {
            bool c, cp;
            cp = nd < d9;  d10 = cp ? d9  : nd;             i10 = cp ? i9  : nj;             c = cp;
            cp = nd < d8;  d9  = cp ? d8  : (c ? nd : d9);  i9  = cp ? i8  : (c ? nj : i9);  c = cp;
            cp = nd < d7;  d8  = cp ? d7  : (c ? nd : d8);  i8  = cp ? i7  : (c ? nj : i8);  c = cp;
            cp = nd < d6;  d7  = cp ? d6  : (c ? nd : d7);  i7  = cp ? i6  : (c ? nj : i7);  c = cp;
            cp = nd < d5;  d6  = cp ? d5  : (c ? nd : d6);  i6  = cp ? i5  : (c ? nj : i6);  c = cp;
            cp = nd < d4;  d5  = cp ? d4  : (c ? nd : d5);  i5  = cp ? i4  : (c ? nj : i5);  c = cp;
            cp = nd < d3;  d4  = cp ? d3  : (c ? nd : d4);  i4  = cp ? i3  : (c ? nj : i4);  c = cp;
            cp = nd < d2v; d3  = cp ? d2v : (c ? nd : d3);  i3  = cp ? i2v : (c ? nj : i3);  c = cp;
            cp = nd < d1;  d2v = cp ? d1  : (c ? nd : d2v); i2v = cp ? i1  : (c ? nj : i2v); c = cp;
            cp = nd < d0;  d1  = cp ? d0  : (c ? nd : d1);  i1  = cp ? i0  : (c ? nj : i1);  c = cp;
            if (c) { d0 = nd; i0 = nj; }
        }
    };

    auto flush = [&]() {
        unsigned long long e = region[tid];   // k=0 prefetch (unused if cnt==0)
#pragma unroll 1
        for (int k = 0; __any(k < cnt); ++k) {
            // next-entry prefetch; k+1 may reach DEPTH -> padded row, in-bounds
            unsigned long long en = region[(k + 1) * NTHR + tid];
            if (k < cnt) {
                float nd = __uint_as_float((unsigned)(e >> 32));
                int   nj = (int)(unsigned)(e & 0xFFFFFFFFull);
                insert(nd, nj);
            }
            e = en;
        }
        cnt = 0;
        // Publish local 11th-best; combine with the cross-wave bound.
        // enc: order-preserving f32 -> u32 (works for all finite values).
        unsigned s10 = __float_as_uint(d10);
        unsigned e10 = (s10 & 0x80000000u) ? ~s10 : (s10 | 0x80000000u);
        unsigned old = atomicMin(&thrG[lane], e10);         // ds_min_rtn_u32
        unsigned eg  = old < e10 ? old : e10;               // current min
        // thr = min(d10, nextafter_up(dec(eg))): strict-< vs thr then equals
        // non-strict <= vs the published bound -> never drops a true member.
        unsigned adj = eg + 1;   // eg <= enc(3e38) here (we just published)
        float gf = (adj & 0x80000000u) ? __uint_as_float(adj & 0x7FFFFFFFu)
                                       : __uint_as_float(~adj);
        thr = fminf(d10, gf);
    };

    auto proc = [&](float cx, float cy, float cz, float sqc, int j) {
        float dot = __fmaf_rn(qz, cz, __fmaf_rn(qy, cy, __fmul_rn(qx, cx)));
        float dd  = __fmaf_rn(-2.0f, dot, __fadd_rn(sqq, sqc)); // == rn(s-2dot)
        if (dd < thr) {
            region[cnt * NTHR + tid] =
                (((unsigned long long)__float_as_uint(dd)) << 32) | (unsigned)j;
            ++cnt;
        }
    };

    // ---- scan: wave streams its 512-candidate slice from global (L2-hot).
    // R13 loop shape (best measured). Forced flush every 64 candidates keeps
    // the shared bound tightening once TRIG stops firing.
    const int base = wave * SLEN;
    const float4* gp = (const float4*)(posb + base * 3);  // 3 float4 per 4 cands
    const float4* sp = (const float4*)(ssq + base);
#pragma unroll 1
    for (int m = 0; m < SLEN; m += 4) {
        int f = (m >> 2) * 3;
        float4 A = gp[f], Bv = gp[f + 1], C = gp[f + 2];
        float4 S = sp[m >> 2];
        int j = base + m;
        proc(A.x,  A.y,  A.z,  S.x, j + 0);
        proc(A.w,  Bv.x, Bv.y, S.y, j + 1);
        proc(Bv.z, Bv.w, C.x,  S.z, j + 2);
        proc(C.y,  C.z,  C.w,  S.w, j + 3);
        if (__any(cnt >= TRIG) || (m & 63) == 60) flush();   // wave-uniform
    }
    flush();

    __syncthreads();   // scans done -> smem becomes merge lists
    float* pd = (float*)smem;                       // [NTHR][11] f32
    int*   pi = (int*)(smem + NTHR * KNN * 4);      // [NTHR][11] i32
    {
        float* pw = pd + tid * KNN;
        int*   iw = pi + tid * KNN;
        pw[0] = d0;  pw[1] = d1;  pw[2] = d2v; pw[3] = d3;  pw[4] = d4;
        pw[5] = d5;  pw[6] = d6;  pw[7] = d7;  pw[8] = d8;  pw[9] = d9;
        pw[10] = d10;
        iw[0] = i0;  iw[1] = i1;  iw[2] = i2v; iw[3] = i3;  iw[4] = i4;
        iw[5] = i5;  iw[6] = i6;  iw[7] = i7;  iw[8] = i8;  iw[9] = i9;
        iw[10] = i10;
    }
    __syncthreads();

    if (tid < QPB) {
        // 16-way merge, lexicographic (d2, idx) == global stable top-11.
        int p[NSLICE]; float hd[NSLICE]; int hi[NSLICE];
#pragma unroll
        for (int s = 0; s < NSLICE; ++s) {
            p[s]  = 0;
            hd[s] = pd[(s * 64 + tid) * KNN];
            hi[s] = pi[(s * 64 + tid) * KNN];
        }
        float acc[6];
#pragma unroll
        for (int c = 0; c < 6; ++c) acc[c] = sW[396 + c];

        for (int r = 0; r < KNN; ++r) {
            float bd = 3.9e38f; int bi = 0x7FFFFFFF; int bs = 0;
#pragma unroll
            for (int s = 0; s < NSLICE; ++s) {
                bool better = (hd[s] < bd) || (hd[s] == bd && hi[s] < bi);
                bs = better ? s : bs;
                bi = better ? hi[s] : bi;
                bd = better ? hd[s] : bd;
            }
            {   // advance winning slice head
                int pp = ++p[bs];
                if (pp < KNN) {
                    hd[bs] = pd[(bs * 64 + tid) * KNN + pp];
                    hi[bs] = pi[(bs * 64 + tid) * KNN + pp];
                } else { hd[bs] = 3.9e38f; hi[bs] = 0x7FFFFFFF; }
            }

            int bg = ((unsigned)bi < (unsigned)NPTS) ? bi : 0;   // defensive

            // velocity features: slots [r*3 .. r*3+2]
            const float* vp = velb + bg * 3;
            float vx = vp[0], vy = vp[1], vz = vp[2];
            const float* w = &sW[r * 18];
#pragma unroll
            for (int c = 0; c < 6; ++c) {
                acc[c] += vx * w[c];
                acc[c] += vy * w[6 + c];
                acc[c] += vz * w[12 + c];
            }
            // offset features (positions from global, L2-hot): rank 0 = self
            if (r >= 1) {
                float ox = posb[bg * 3 + 0] - qx;
                float oy = posb[bg * 3 + 1] - qy;
                float oz = posb[bg * 3 + 2] - qz;
                const float* w2 = &sW[(33 + (r - 1) * 3) * 6];
#pragma unroll
                for (int c = 0; c < 6; ++c) {
                    acc[c] += ox * w2[c];
                    acc[c] += oy * w2[6 + c];
                    acc[c] += oz * w2[12 + c];
                }
            }
        }
        // init_config features: slots [63..65]
#pragma unroll
        for (int k3 = 0; k3 < 3; ++k3) {
            const float* w3 = &sW[(63 + k3) * 6];
            float iv = sW[402 + k3];
#pragma unroll
            for (int c = 0; c < 6; ++c) acc[c] += iv * w3[c];
        }
        acc[0] += qx; acc[1] += qy; acc[2] += qz;

        float* op = out + (b * NPTS + q) * 6;
#pragma unroll
        for (int c = 0; c < 6; ++c) op[c] = acc[c];
    }
}

extern "C" void kernel_launch(void* const* d_in, const int* in_sizes, int n_in,
                              void* d_out, int out_size, void* d_ws, size_t ws_size,
                              hipStream_t stream) {
    (void)in_sizes; (void)n_in; (void)out_size; (void)d_ws; (void)ws_size;
    const float* pos   = (const float*)d_in[0];
    const float* vel   = (const float*)d_in[1];
    const float* initc = (const float*)d_in[2];
    const float* W1    = (const float*)d_in[3];
    const float* b1    = (const float*)d_in[4];
    const float* W2    = (const float*)d_in[5];
    const float* b2    = (const float*)d_in[6];
    const float* W3    = (const float*)d_in[7];
    const float* b3    = (const float*)d_in[8];
    float* out = (float*)d_out;

    knn_mlp<<<256, NTHR, 0, stream>>>(pos, vel, initc, W1, b1, W2, b2, W3, b3, out);
}

// Round 6
// 190.525 us; speedup vs baseline: 1.0263x; 1.0263x over previous
//
#include <hip/hip_runtime.h>

// B=2, N=8192, K=10, I=3, LEN_IN=66. All buffers f32.
// LOCKED correctness recipe (R8-R12, passed, absmax 0.0625):
//   sq  = fmaf(z,z, fmaf(y,y, rn(x*x)))          (asc FMA)
//   dot = fmaf(z,z', fmaf(y,y', rn(x*x')))       (asc FMA)
//   d2  = fmaf(-2,dot, rn(sq_q + sq_c))          (== single-rounded sub form)
//   selection: strict <, stable lowest-index-first (lexicographic (d2,idx))
// R19: ISOLATED cross-wave threshold (R16 post-mortem).
//   R16 bundled 5 deltas vs the 117.4us R13 baseline and regressed to 147.6
//   (VALUBusy 70->92%, +128K VALU cyc/SIMD — unexplainable by the ~20-inst
//   publish tail; some bundled change poisoned hot-loop codegen). R19 is
//   EXACT R13 (DEPTH=10, TRIG=7, direct region read in flush, no forced
//   flush, no prefetch, no readfirstlane) plus ONLY the publish tail:
//   at each flush end, publish enc(d10) to thrG[lane] via ds_min_rtn_u32,
//   set thr = min(d10, nextafter_up(dec(min_published))).
//   Safety: every wave's d10 (11th-best over a subset) >= global 11th at
//   all times, so thr >= global_11th + 1ulp on the shared side; a pruned
//   candidate has dd >= thr > global_11th -> not in the global top-11
//   (ties dd == global_11th < thr still pass). A surviving global-top-11
//   element can never be evicted from its slice list (11 in-slice better
//   elements would contradict membership). Merge unchanged -> exact.
#define NPTS   8192
#define KNN    11
#define QPB    64          // queries per block (one per lane)
#define NTHR   1024
#define NSLICE 16          // candidate slices (one per wave)
#define SLEN   (NPTS / NSLICE)   // 512
#define DEPTH  10          // per-lane push-buffer entries (R13 value)
#define TRIG   7           // flush when any lane cnt >= TRIG (4 pushes headroom)

__global__ __launch_bounds__(NTHR, 4) void knn_mlp(
    const float* __restrict__ pos,
    const float* __restrict__ vel,
    const float* __restrict__ initc,
    const float* __restrict__ W1,
    const float* __restrict__ b1,
    const float* __restrict__ W2,
    const float* __restrict__ b2,
    const float* __restrict__ W3,
    const float* __restrict__ b3,
    float* __restrict__ out) {

    // Phased LDS (112KB):
    //   phase-scan : [0,32K) ssq | [32K,112K) push region [k][tid] u64
    //   phase-fold : [32K, ...) fold scratch (4.3KB)
    //   phase-merge: [0,45K) pd f32 | [45K,90K) pi i32   (ssq/region dead)
    __shared__ __align__(16) char smem[32 * 1024 + NTHR * DEPTH * 8];
    __shared__ float sW[405];           // Weff[396] + bias[6] + init[3]
    __shared__ unsigned thrG[QPB];      // per-query shared bound, enc-domain

    float* ssq = (float*)smem;
    unsigned long long* region = (unsigned long long*)(smem + 32 * 1024);

    const int tid  = threadIdx.x;
    const int lane = tid & 63;
    const int wave = tid >> 6;
    const int b    = blockIdx.x >> 7;           // 128 blocks per batch
    const int n0   = (blockIdx.x & 127) * QPB;
    const int q    = n0 + lane;

    const float* posb = pos + b * NPTS * 3;
    const float* velb = vel + b * NPTS * 3;

    // ---- phase 1a: per-point sq into LDS (LOCKED recipe)
    for (int a = tid; a < NPTS; a += NTHR) {
        float x = posb[a * 3 + 0];
        float y = posb[a * 3 + 1];
        float z = posb[a * 3 + 2];
        ssq[a] = __fmaf_rn(z, z, __fmaf_rn(y, y, __fmul_rn(x, x)));
    }
    // ---- phase 1b: fold stage 1 (scratch in region): W12 = W1@W2, b12 = b1@W2+b2
    float* sW12 = (float*)region;
    for (int e = tid; e < 66 * 16; e += NTHR) {
        int r = e >> 4, c = e & 15;
        float s = 0.f;
        for (int j = 0; j < 32; ++j) s += W1[r * 32 + j] * W2[j * 16 + c];
        sW12[e] = s;
    }
    if (tid < 16) {
        float s = b2[tid];
        for (int j = 0; j < 32; ++j) s += b1[j] * W2[j * 16 + tid];
        sW12[66 * 16 + tid] = s;
    }
    if (tid < 3) sW[402 + tid] = initc[b * 3 + tid];
    if (tid < QPB) thrG[tid] = 0xFF800000u;     // enc(+inf): no bound yet
    __syncthreads();
    // ---- fold stage 2: Weff = W12@W3, bias = b12@W3 + b3
    for (int e = tid; e < 66 * 6; e += NTHR) {
        int r = e / 6, c = e - r * 6;
        float s = 0.f;
        for (int j = 0; j < 16; ++j) s += sW12[r * 16 + j] * W3[j * 6 + c];
        sW[e] = s;
    }
    if (tid < 6) {
        float s = b3[tid];
        for (int j = 0; j < 16; ++j) s += sW12[66 * 16 + j] * W3[j * 6 + tid];
        sW[396 + tid] = s;
    }
    __syncthreads();   // fold scratch done -> region becomes push buffers

    const float qx = posb[q * 3 + 0];
    const float qy = posb[q * 3 + 1];
    const float qz = posb[q * 3 + 2];
    const float sqq = ssq[q];           // identical bits to locked recipe

    // Top-11 in NAMED SCALARS (forced register residency; R12 demoted arrays).
    float d0 = 3.0e38f, d1 = 3.0e38f, d2v = 3.0e38f, d3 = 3.0e38f, d4 = 3.0e38f,
          d5 = 3.0e38f, d6 = 3.0e38f, d7 = 3.0e38f, d8 = 3.0e38f, d9 = 3.0e38f,
          d10 = 3.0e38f;
    int   i0 = 0x7FFFFFFF, i1 = 0x7FFFFFFF, i2v = 0x7FFFFFFF, i3 = 0x7FFFFFFF,
          i4 = 0x7FFFFFFF, i5 = 0x7FFFFFFF, i6 = 0x7FFFFFFF, i7 = 0x7FFFFFFF,
          i8 = 0x7FFFFFFF, i9 = 0x7FFFFFFF, i10 = 0x7FFFFFFF;

    float thr = 3.0e38f;       // combined bound; only over-buffers, never drops
    int cnt = 0;

    // Hand-unrolled stable insert (identical semantics to the array loop).
    auto insert = [&](float nd, int nj) {
        if (nd < d10) {
            bool c, cp;
            cp = nd < d9;  d10 = cp ? d9  : nd;             i10 = cp ? i9  : nj;             c = cp;
            cp = nd < d8;  d9  = cp ? d8  : (c ? nd : d9);  i9  = cp ? i8  : (c ? nj : i9);  c = cp;
            cp = nd < d7;  d8  = cp ? d7  : (c ? nd : d8);  i8  = cp ? i7  : (c ? nj : i8);  c = cp;
            cp = nd < d6;  d7  = cp ? d6  : (c ? nd : d7);  i7  = cp ? i6  : (c ? nj : i7);  c = cp;
            cp = nd < d5;  d6  = cp ? d5  : (c ? nd : d6);  i6  = cp ? i5  : (c ? nj : i6);  c = cp;
            cp = nd < d4;  d5  = cp ? d4  : (c ? nd : d5);  i5  = cp ? i4  : (c ? nj : i5);  c = cp;
            cp = nd < d3;  d4  = cp ? d3  : (c ? nd : d4);  i4  = cp ? i3  : (c ? nj : i4);  c = cp;
            cp = nd < d2v; d3  = cp ? d2v : (c ? nd : d3);  i3  = cp ? i2v : (c ? nj : i3);  c = cp;
            cp = nd < d1;  d2v = cp ? d1  : (c ? nd : d2v); i2v = cp ? i1  : (c ? nj : i2v); c = cp;
            cp = nd < d0;  d1  = cp ? d0  : (c ? nd : d1);  i1  = cp ? i0  : (c ? nj : i1);  c = cp;
            if (c) { d0 = nd; i0 = nj; }
        }
    };

    auto flush = [&]() {
#pragma unroll 1
        for (int k = 0; __any(k < cnt); ++k) {
            if (k < cnt) {
                unsigned long long e = region[k * NTHR + tid];  // [k][tid]: 2-way only
                float nd = __uint_as_float((unsigned)(e >> 32));
                int   nj = (int)(unsigned)(e & 0xFFFFFFFFull);
                insert(nd, nj);
            }
        }
        cnt = 0;
        // R19 publish tail (~12 VALU + 1 ds_min_rtn_u32, rare path only).
        // enc: order-preserving f32 -> u32 for finite values.
        unsigned s10 = __float_as_uint(d10);
        unsigned e10 = (s10 & 0x80000000u) ? ~s10 : (s10 | 0x80000000u);
        unsigned old = atomicMin(&thrG[lane], e10);
        unsigned eg  = old < e10 ? old : e10;               // current min
        unsigned adj = eg + 1;   // eg <= enc(3e38) (we just published) -> no overflow
        float gf = (adj & 0x80000000u) ? __uint_as_float(adj & 0x7FFFFFFFu)
                                       : __uint_as_float(~adj);
        thr = fminf(d10, gf);    // strict-< vs thr == non-strict vs published bound
    };

    auto proc = [&](float cx, float cy, float cz, float sqc, int j) {
        float dot = __fmaf_rn(qz, cz, __fmaf_rn(qy, cy, __fmul_rn(qx, cx)));
        float dd  = __fmaf_rn(-2.0f, dot, __fadd_rn(sqq, sqc)); // == rn(s-2dot)
        if (dd < thr) {
            region[cnt * NTHR + tid] =
                (((unsigned long long)__float_as_uint(dd)) << 32) | (unsigned)j;
            ++cnt;
        }
    };

    // ---- scan: wave streams its 512-candidate slice from global (L2-hot).
    // EXACT R13 loop shape (117.4us, best measured).
    const int base = wave * SLEN;
    const float4* gp = (const float4*)(posb + base * 3);  // 3 float4 per 4 cands
    const float4* sp = (const float4*)(ssq + base);
#pragma unroll 1
    for (int m = 0; m < SLEN; m += 4) {
        int f = (m >> 2) * 3;
        float4 A = gp[f], Bv = gp[f + 1], C = gp[f + 2];
        float4 S = sp[m >> 2];
        int j = base + m;
        proc(A.x,  A.y,  A.z,  S.x, j + 0);
        proc(A.w,  Bv.x, Bv.y, S.y, j + 1);
        proc(Bv.z, Bv.w, C.x,  S.z, j + 2);
        proc(C.y,  C.z,  C.w,  S.w, j + 3);
        if (__any(cnt >= TRIG)) flush();                  // rare wave-uniform path
    }
    flush();

    __syncthreads();   // scans done -> smem becomes merge lists
    float* pd = (float*)smem;                       // [NTHR][11] f32
    int*   pi = (int*)(smem + NTHR * KNN * 4);      // [NTHR][11] i32
    {
        float* pw = pd + tid * KNN;
        int*   iw = pi + tid * KNN;
        pw[0] = d0;  pw[1] = d1;  pw[2] = d2v; pw[3] = d3;  pw[4] = d4;
        pw[5] = d5;  pw[6] = d6;  pw[7] = d7;  pw[8] = d8;  pw[9] = d9;
        pw[10] = d10;
        iw[0] = i0;  iw[1] = i1;  iw[2] = i2v; iw[3] = i3;  iw[4] = i4;
        iw[5] = i5;  iw[6] = i6;  iw[7] = i7;  iw[8] = i8;  iw[9] = i9;
        iw[10] = i10;
    }
    __syncthreads();

    if (tid < QPB) {
        // 16-way merge, lexicographic (d2, idx) == global stable top-11.
        int p[NSLICE]; float hd[NSLICE]; int hi[NSLICE];
#pragma unroll
        for (int s = 0; s < NSLICE; ++s) {
            p[s]  = 0;
            hd[s] = pd[(s * 64 + tid) * KNN];
            hi[s] = pi[(s * 64 + tid) * KNN];
        }
        float acc[6];
#pragma unroll
        for (int c = 0; c < 6; ++c) acc[c] = sW[396 + c];

        for (int r = 0; r < KNN; ++r) {
            float bd = 3.9e38f; int bi = 0x7FFFFFFF; int bs = 0;
#pragma unroll
            for (int s = 0; s < NSLICE; ++s) {
                bool better = (hd[s] < bd) || (hd[s] == bd && hi[s] < bi);
                bs = better ? s : bs;
                bi = better ? hi[s] : bi;
                bd = better ? hd[s] : bd;
            }
            {   // advance winning slice head
                int pp = ++p[bs];
                if (pp < KNN) {
                    hd[bs] = pd[(bs * 64 + tid) * KNN + pp];
                    hi[bs] = pi[(bs * 64 + tid) * KNN + pp];
                } else { hd[bs] = 3.9e38f; hi[bs] = 0x7FFFFFFF; }
            }

            int bg = ((unsigned)bi < (unsigned)NPTS) ? bi : 0;   // defensive

            // velocity features: slots [r*3 .. r*3+2]
            const float* vp = velb + bg * 3;
            float vx = vp[0], vy = vp[1], vz = vp[2];
            const float* w = &sW[r * 18];
#pragma unroll
            for (int c = 0; c < 6; ++c) {
                acc[c] += vx * w[c];
                acc[c] += vy * w[6 + c];
                acc[c] += vz * w[12 + c];
            }
            // offset features (positions from global, L2-hot): rank 0 = self
            if (r >= 1) {
                float ox = posb[bg * 3 + 0] - qx;
                float oy = posb[bg * 3 + 1] - qy;
                float oz = posb[bg * 3 + 2] - qz;
                const float* w2 = &sW[(33 + (r - 1) * 3) * 6];
#pragma unroll
                for (int c = 0; c < 6; ++c) {
                    acc[c] += ox * w2[c];
                    acc[c] += oy * w2[6 + c];
                    acc[c] += oz * w2[12 + c];
                }
            }
        }
        // init_config features: slots [63..65]
#pragma unroll
        for (int k3 = 0; k3 < 3; ++k3) {
            const float* w3 = &sW[(63 + k3) * 6];
            float iv = sW[402 + k3];
#pragma unroll
            for (int c = 0; c < 6; ++c) acc[c] += iv * w3[c];
        }
        acc[0] += qx; acc[1] += qy; acc[2] += qz;

        float* op = out + (b * NPTS + q) * 6;
#pragma unroll
        for (int c = 0; c < 6; ++c) op[c] = acc[c];
    }
}

extern "C" void kernel_launch(void* const* d_in, const int* in_sizes, int n_in,
                              void* d_out, int out_size, void* d_ws, size_t ws_size,
                              hipStream_t stream) {
    (void)in_sizes; (void)n_in; (void)out_size; (void)d_ws; (void)ws_size;
    const float* pos   = (const float*)d_in[0];
    const float* vel   = (const float*)d_in[1];
    const float* initc = (const float*)d_in[2];
    const float* W1    = (const float*)d_in[3];
    const float* b1    = (const float*)d_in[4];
    const float* W2    = (const float*)d_in[5];
    const float* b2    = (const float*)d_in[6];
    const float* W3    = (const float*)d_in[7];
    const float* b3    = (const float*)d_in[8];
    float* out = (float*)d_out;

    knn_mlp<<<256, NTHR, 0, stream>>>(pos, vel, initc, W1, b1, W2, b2, W3, b3, out);
}